// Round 1
// baseline (246.691 us; speedup 1.0000x reference)
//
#include <hip/hip_runtime.h>

#define NBATCH 32
#define NH 16
#define NT 16
#define DD 64
#define SS 1024
#define LL 1024
#define TOTK 2064
#define EE 1024

typedef __attribute__((ext_vector_type(8))) short bf16x8;
typedef __attribute__((ext_vector_type(4))) float f32x4;

__device__ __forceinline__ unsigned short f2bf(float x) {
  union { float f; unsigned u; } v; v.f = x;
  unsigned r = v.u + 0x7fffu + ((v.u >> 16) & 1u);
  return (unsigned short)(r >> 16);
}

// ---------------- QKV projection ----------------
// grid (4 mtiles, 48 ntiles), 256 threads. ntile -> (mat = ntile>>4, h = ntile&15)
__global__ __launch_bounds__(256)
void proj_kernel(const float* __restrict__ hidden,
                 const float* __restrict__ Wq, const float* __restrict__ bq,
                 const float* __restrict__ Wk, const float* __restrict__ bk,
                 const float* __restrict__ Wv, const float* __restrict__ bv,
                 unsigned short* __restrict__ qws,
                 float* __restrict__ kws, float* __restrict__ vws)
{
  __shared__ alignas(16) unsigned short As[128][40];  // rows padded to 80B (16B mult)
  __shared__ alignas(16) unsigned short Bs[64][40];
  const int mtile = blockIdx.x;
  const int ntile = blockIdx.y;
  const int mat = ntile >> 4;
  const int h = ntile & 15;
  const float* Wm = (mat == 0) ? Wq : (mat == 1 ? Wk : Wv);
  const float* bm = (mat == 0) ? bq : (mat == 1 ? bk : bv);
  const int tid = threadIdx.x;
  const int lane = tid & 63, w = tid >> 6;
  const int lr = lane & 15, lg = lane >> 4;
  const int m0 = mtile * 128;

  const f32x4 fz = {0.f, 0.f, 0.f, 0.f};
  f32x4 acc[2][4];
  #pragma unroll
  for (int i = 0; i < 2; ++i)
    #pragma unroll
    for (int j = 0; j < 4; ++j) acc[i][j] = fz;

  for (int k0 = 0; k0 < EE; k0 += 32) {
    __syncthreads();
    // stage A: 128 rows x 32 cols fp32 -> bf16
    #pragma unroll
    for (int it = 0; it < 4; ++it) {
      int idx = it * 256 + tid;
      int row = idx >> 3, c4 = idx & 7;
      float4 v = *(const float4*)(hidden + (m0 + row) * EE + k0 + c4 * 4);
      ushort4 b = make_ushort4(f2bf(v.x), f2bf(v.y), f2bf(v.z), f2bf(v.w));
      *(ushort4*)(&As[row][c4 * 4]) = b;
    }
    // stage B: 64 feature rows x 32 cols
    #pragma unroll
    for (int it = 0; it < 2; ++it) {
      int idx = it * 256 + tid;
      int row = idx >> 3, c4 = idx & 7;
      float4 v = *(const float4*)(Wm + (h * 64 + row) * EE + k0 + c4 * 4);
      ushort4 b = make_ushort4(f2bf(v.x), f2bf(v.y), f2bf(v.z), f2bf(v.w));
      *(ushort4*)(&Bs[row][c4 * 4]) = b;
    }
    __syncthreads();
    bf16x8 a0 = *(const bf16x8*)(&As[w * 32 + lr][lg * 8]);
    bf16x8 a1 = *(const bf16x8*)(&As[w * 32 + 16 + lr][lg * 8]);
    #pragma unroll
    for (int dt = 0; dt < 4; ++dt) {
      bf16x8 bb = *(const bf16x8*)(&Bs[dt * 16 + lr][lg * 8]);
      acc[0][dt] = __builtin_amdgcn_mfma_f32_16x16x32_bf16(a0, bb, acc[0][dt], 0, 0, 0);
      acc[1][dt] = __builtin_amdgcn_mfma_f32_16x16x32_bf16(a1, bb, acc[1][dt], 0, 0, 0);
    }
  }

  // epilogue: C/D map col=lane&15, row=(lane>>4)*4+reg  [HW-verified]
  #pragma unroll
  for (int rb = 0; rb < 2; ++rb)
    #pragma unroll
    for (int dt = 0; dt < 4; ++dt)
      #pragma unroll
      for (int r = 0; r < 4; ++r) {
        int Mrow = m0 + w * 32 + rb * 16 + lg * 4 + r;
        int nb = Mrow >> 4, t = Mrow & 15;
        int d = dt * 16 + lr;
        float val = acc[rb][dt][r] + bm[h * 64 + d];
        int oi = ((nb * NH + h) * NT + t) * DD + d;
        if (mat == 0) qws[oi] = f2bf(val);
        else if (mat == 1) kws[oi] = val;
        else vws[oi] = val;
      }
}

// ---------------- fused prefix attention ----------------
struct alignas(16) WaveBuf {
  unsigned short K[32][72];   // key tile, rows 144B (16B mult), d-major
  unsigned short Vt[64][40];  // V transposed [d][j], rows 80B
  unsigned short P[16][40];   // probs [t][j], rows 80B
};                            // 11008 B, 16B multiple
struct alignas(16) MergeBuf { float ctx[4][16][64]; float ml[4][16][2]; };
union SmemU { WaveBuf wb[4]; MergeBuf mg; };

__global__ __launch_bounds__(256)
void attn_kernel(const float* __restrict__ mask, const float* __restrict__ rel,
                 const float* __restrict__ ppk, const float* __restrict__ ppv,
                 const float* __restrict__ pk, const float* __restrict__ pv,
                 const unsigned short* __restrict__ qws,
                 const float* __restrict__ kws, const float* __restrict__ vws,
                 float* __restrict__ out)
{
  __shared__ SmemU sm;
  const int wg = blockIdx.x;       // 512 = 32 nb * 16 h
  const int nb = wg >> 4, h = wg & 15;
  const int n = nb >> 2;           // B = 4
  const int tid = threadIdx.x;
  const int lane = tid & 63, w = tid >> 6;
  const int lr = lane & 15, lg = lane >> 4;
  WaveBuf& WB = sm.wb[w];

  // Q fragments (A operand): row = lane&15 (t), k = (lane>>4)*8+e (d)
  const unsigned short* qbase = qws + ((nb * NH + h) * NT) * DD;
  bf16x8 aq0 = *(const bf16x8*)(qbase + lr * DD + lg * 8);
  bf16x8 aq1 = *(const bf16x8*)(qbase + lr * DD + lg * 8 + 32);

  const float* relbase = rel + ((nb * NH + h) * NT) * TOTK;
  const float* mbase = mask + nb * TOTK;

  float m_r[4], l_r[4];
  const f32x4 fz = {0.f, 0.f, 0.f, 0.f};
  f32x4 ctx[4];
  #pragma unroll
  for (int r = 0; r < 4; ++r) { m_r[r] = -1e30f; l_r[r] = 0.f; }
  #pragma unroll
  for (int dt = 0; dt < 4; ++dt) ctx[dt] = fz;

  // 65 key tiles of 32: [0,32)=prefix, [32,64)=past, 64=new (16 valid)
  for (int tt = w; tt < 65; tt += 4) {
    const float* ksrc; const float* vsrc;
    int jabs0, valid;
    if (tt < 32) {
      int j = tt * 32;
      ksrc = ppk + ((n * NH + h) * SS + j) * DD;
      vsrc = ppv + ((n * NH + h) * SS + j) * DD;
      jabs0 = j; valid = 32;
    } else if (tt < 64) {
      int j = (tt - 32) * 32;
      ksrc = pk + ((nb * NH + h) * LL + j) * DD;
      vsrc = pv + ((nb * NH + h) * LL + j) * DD;
      jabs0 = SS + j; valid = 32;
    } else {
      ksrc = kws + ((nb * NH + h) * NT) * DD;
      vsrc = vws + ((nb * NH + h) * NT) * DD;
      jabs0 = SS + LL; valid = 16;
    }

    // stage K: 32 rows x 64 d, fp32 -> bf16 (coalesced float4)
    #pragma unroll
    for (int it = 0; it < 8; ++it) {
      int idx = it * 64 + lane;
      int row = idx >> 4, c4 = idx & 15;
      float4 v = make_float4(0.f, 0.f, 0.f, 0.f);
      if (row < valid) v = *(const float4*)(ksrc + row * DD + c4 * 4);
      ushort4 b = make_ushort4(f2bf(v.x), f2bf(v.y), f2bf(v.z), f2bf(v.w));
      *(ushort4*)(&WB.K[row][c4 * 4]) = b;
    }
    // stage V transposed: lane owns column d = lane
    #pragma unroll
    for (int jj = 0; jj < 8; ++jj) {
      float v0 = (jj * 4 + 0 < valid) ? vsrc[(jj * 4 + 0) * DD + lane] : 0.f;
      float v1 = (jj * 4 + 1 < valid) ? vsrc[(jj * 4 + 1) * DD + lane] : 0.f;
      float v2 = (jj * 4 + 2 < valid) ? vsrc[(jj * 4 + 2) * DD + lane] : 0.f;
      float v3 = (jj * 4 + 3 < valid) ? vsrc[(jj * 4 + 3) * DD + lane] : 0.f;
      ushort4 b = make_ushort4(f2bf(v0), f2bf(v1), f2bf(v2), f2bf(v3));
      *(ushort4*)(&WB.Vt[lane][jj * 4]) = b;
    }

    // QK^T: two 16-key blocks, K=64 via two chained MFMAs each
    float sc0[4], sc1[4];
    #pragma unroll
    for (int sub = 0; sub < 2; ++sub) {
      bf16x8 bk0 = *(const bf16x8*)(&WB.K[sub * 16 + lr][lg * 8]);
      bf16x8 bk1 = *(const bf16x8*)(&WB.K[sub * 16 + lr][lg * 8 + 32]);
      f32x4 s = fz;
      s = __builtin_amdgcn_mfma_f32_16x16x32_bf16(aq0, bk0, s, 0, 0, 0);
      s = __builtin_amdgcn_mfma_f32_16x16x32_bf16(aq1, bk1, s, 0, 0, 0);
      int jloc = sub * 16 + lr;
      int jabs = jabs0 + jloc;
      bool jok = jloc < valid;
      float mval = jok ? mbase[jabs] : 0.f;
      #pragma unroll
      for (int r = 0; r < 4; ++r) {
        int t = lg * 4 + r;
        float v = jok ? (s[r] * 0.125f + relbase[t * TOTK + jabs] + mval) : -1e30f;
        if (sub == 0) sc0[r] = v; else sc1[r] = v;
      }
    }

    // online softmax (rows t = lg*4+r live across the 16 lanes of this group)
    #pragma unroll
    for (int r = 0; r < 4; ++r) {
      float tmax = fmaxf(sc0[r], sc1[r]);
      #pragma unroll
      for (int o = 8; o >= 1; o >>= 1) tmax = fmaxf(tmax, __shfl_xor(tmax, o, 16));
      float mnew = fmaxf(m_r[r], tmax);
      float alpha = expf(m_r[r] - mnew);
      float p0 = expf(sc0[r] - mnew);
      float p1 = expf(sc1[r] - mnew);
      float rs = p0 + p1;
      #pragma unroll
      for (int o = 8; o >= 1; o >>= 1) rs += __shfl_xor(rs, o, 16);
      l_r[r] = l_r[r] * alpha + rs;
      m_r[r] = mnew;
      #pragma unroll
      for (int dt = 0; dt < 4; ++dt) ctx[dt][r] *= alpha;
      int t = lg * 4 + r;
      WB.P[t][lr] = f2bf(p0);
      WB.P[t][16 + lr] = f2bf(p1);
    }

    // PV: A = P (k over 32 keys), B = Vt rows (contiguous j) — identical k index math
    bf16x8 pa = *(const bf16x8*)(&WB.P[lr][lg * 8]);
    #pragma unroll
    for (int dt = 0; dt < 4; ++dt) {
      bf16x8 bv_ = *(const bf16x8*)(&WB.Vt[dt * 16 + lr][lg * 8]);
      ctx[dt] = __builtin_amdgcn_mfma_f32_16x16x32_bf16(pa, bv_, ctx[dt], 0, 0, 0);
    }
  }

  // merge the 4 waves' partial (m, l, ctx)
  __syncthreads();
  #pragma unroll
  for (int dt = 0; dt < 4; ++dt)
    #pragma unroll
    for (int r = 0; r < 4; ++r)
      sm.mg.ctx[w][lg * 4 + r][dt * 16 + lr] = ctx[dt][r];
  if (lr == 0) {
    #pragma unroll
    for (int r = 0; r < 4; ++r) {
      sm.mg.ml[w][lg * 4 + r][0] = m_r[r];
      sm.mg.ml[w][lg * 4 + r][1] = l_r[r];
    }
  }
  __syncthreads();
  #pragma unroll
  for (int i = 0; i < 4; ++i) {
    int idx = i * 256 + tid;
    int t = idx >> 6, d = idx & 63;
    float M = -1e30f;
    #pragma unroll
    for (int ww = 0; ww < 4; ++ww) M = fmaxf(M, sm.mg.ml[ww][t][0]);
    float num = 0.f, den = 0.f;
    #pragma unroll
    for (int ww = 0; ww < 4; ++ww) {
      float e = expf(sm.mg.ml[ww][t][0] - M);
      den += sm.mg.ml[ww][t][1] * e;
      num += sm.mg.ctx[ww][t][d] * e;
    }
    out[((nb * NT + t) * NH + h) * DD + d] = num / den;
  }
}

extern "C" void kernel_launch(void* const* d_in, const int* in_sizes, int n_in,
                              void* d_out, int out_size, void* d_ws, size_t ws_size,
                              hipStream_t stream) {
  const float* hidden = (const float*)d_in[0];
  const float* mask   = (const float*)d_in[1];
  const float* rel    = (const float*)d_in[2];
  const float* ppk    = (const float*)d_in[3];
  const float* ppv    = (const float*)d_in[4];
  const float* pk     = (const float*)d_in[5];
  const float* pv     = (const float*)d_in[6];
  const float* Wq     = (const float*)d_in[7];
  const float* bq     = (const float*)d_in[8];
  const float* Wk     = (const float*)d_in[9];
  const float* bk     = (const float*)d_in[10];
  const float* Wv     = (const float*)d_in[11];
  const float* bv     = (const float*)d_in[12];
  float* out = (float*)d_out;

  unsigned short* qws = (unsigned short*)d_ws;                 // 1 MB bf16 Q
  float* kws = (float*)((char*)d_ws + (1 << 20));              // 2 MB fp32 new K
  float* vws = (float*)((char*)d_ws + 3 * (1 << 20));          // 2 MB fp32 new V

  proj_kernel<<<dim3(4, 48), 256, 0, stream>>>(hidden, Wq, bq, Wk, bk, Wv, bv,
                                               qws, kws, vws);
  attn_kernel<<<dim3(512), 256, 0, stream>>>(mask, rel, ppk, ppv, pk, pv,
                                             qws, kws, vws, out);
}